// Round 6
// baseline (3912.506 us; speedup 1.0000x reference)
//
#include <hip/hip_runtime.h>
#include <hip/hip_bf16.h>
#include <stdint.h>
#include <stddef.h>

using bf16 = __hip_bfloat16;
typedef short s16x8 __attribute__((ext_vector_type(8)));   // 8 bf16 = one MFMA frag (4 VGPRs)
typedef float f32x4 __attribute__((ext_vector_type(4)));

#define MFMA16(a, b, c) __builtin_amdgcn_mfma_f32_16x16x32_bf16((a), (b), (c), 0, 0, 0)

typedef __attribute__((address_space(1))) void gvoid;
typedef __attribute__((address_space(3))) void lvoid;
// global -> LDS direct copy, 16B per lane; LDS dest = wave-uniform base + lane*16
#define GLL16(gp, lp) __builtin_amdgcn_global_load_lds((gvoid*)(void*)(gp), (lvoid*)(lp), 16, 0, 0)

__device__ __forceinline__ short f2bf(float x) {
    bf16 h = __float2bfloat16(x);
    return __builtin_bit_cast(short, h);
}

// f32 -> bf16 elementwise, n % 1024 == 0, grid*block*4 == n
__global__ void cvt_bf16(const float* __restrict__ in, bf16* __restrict__ out, int n) {
    int i = (blockIdx.x * blockDim.x + threadIdx.x) * 4;
    if (i < n) {
        float4 v = *(const float4*)(in + i);
        out[i + 0] = __float2bfloat16(v.x);
        out[i + 1] = __float2bfloat16(v.y);
        out[i + 2] = __float2bfloat16(v.z);
        out[i + 3] = __float2bfloat16(v.w);
    }
}

// zero n bf16 (n % 2048 == 0), grid*block*8 == n
__global__ void zero_bf16(bf16* __restrict__ p, int n) {
    int i = (blockIdx.x * blockDim.x + threadIdx.x) * 8;
    if (i < n) {
        s16x8 z = {0, 0, 0, 0, 0, 0, 0, 0};
        *(s16x8*)(p + i) = z;
    }
}

// 1024x1024 bf16 transpose: out = in^T.  grid (16,16), block 256.
__global__ __launch_bounds__(256) void transpose_bf16(
    const bf16* __restrict__ in, bf16* __restrict__ out)
{
    __shared__ bf16 t[64][72];
    const int bx = blockIdx.x * 64, by = blockIdx.y * 64;
    const int tid = threadIdx.x;
#pragma unroll
    for (int i = 0; i < 2; ++i) {
        const int r = (tid >> 3) + i * 32, c = (tid & 7) * 8;
        *(s16x8*)&t[r][c] = *(const s16x8*)(in + (size_t)(bx + r) * 1024 + by + c);
    }
    __syncthreads();
#pragma unroll
    for (int i = 0; i < 2; ++i) {
        const int r = (tid >> 3) + i * 32, c = (tid & 7) * 8;
        s16x8 v;
#pragma unroll
        for (int k = 0; k < 8; ++k) v[k] = __builtin_bit_cast(short, t[c + k][r]);
        *(s16x8*)(out + (size_t)(by + r) * 1024 + bx + c) = v;
    }
}

// ===========================================================================
// Persistent fused chunk-scan (replaces Phase-A GEMM + 15 local_step launches).
// Block c (of 32) owns chunk c: for j = 0..15, t = c*16+j:
//   A[t] = X[t] @ Wax^T + ba + (j>0 ? A[t-1] @ Waa^T : 0)
// State A[t-1] (64x1024 bf16 = 128 KB) lives in LDS, slot-XOR-swizzled.
// Operands need NO LDS staging: X A-frags load straight from global
// (f32 -> bf16 cvt in regs; 4 quads cover 128 contiguous B per row), W B-frags
// stream from L2 (2 MB, shared by the 4 blocks/XCD -> L2-resident).
// 8 waves, each computes all 64 m-rows x a 128-col n-slice (acc 128 f32/lane
// -> AGPRs).  2 barriers per step, zero launches between steps.
// MFMA-issue floor: 2048 MFMA/wave/step -> ~8.3 us/step, ~133 us total.
// ===========================================================================
__global__ __launch_bounds__(512, 2) void chunk_scan(
    const float* __restrict__ X,      // [64][512][1024] f32
    const bf16* __restrict__ Waxb,    // [1024][1024] bf16
    const bf16* __restrict__ Waab,    // [1024][1024] bf16
    const float* __restrict__ ba,     // [1024] f32
    bf16* __restrict__ UA)            // [512][64][1024] bf16
{
    __shared__ __align__(16) bf16 lA[64 * 1024];   // 128 KB state, swizzled

    const int tid  = threadIdx.x;
    const int lane = tid & 63, wv = tid >> 6;      // 8 waves
    const int quad = lane >> 4, l16 = lane & 15;
    const int n0w  = wv * 128;                     // wave's n-slice
    const int c    = blockIdx.x;                   // chunk 0..31

    float bv[8];
#pragma unroll
    for (int nt = 0; nt < 8; ++nt) bv[nt] = ba[n0w + nt * 16 + l16];

    for (int j = 0; j < 16; ++j) {
        const int t = c * 16 + j;
        f32x4 acc[4][8] = {};   // [mt][nt]

        // ---- X-phase: acc = X[t] @ Wax^T  (A-frags direct from global f32)
#pragma unroll 2
        for (int kt = 0; kt < 16; ++kt) {
#pragma unroll
            for (int kc = 0; kc < 2; ++kc) {
                const int kb = kt * 64 + kc * 32 + quad * 8;   // k elem base
                s16x8 af[4];
#pragma unroll
                for (int mt = 0; mt < 4; ++mt) {
                    const int m = 16 * mt + l16;
                    const float* xp = X + ((size_t)m * 512 + t) * 1024 + kb;
                    float4 v0 = *(const float4*)xp;
                    float4 v1 = *(const float4*)(xp + 4);
                    s16x8 w;
                    w[0] = f2bf(v0.x); w[1] = f2bf(v0.y); w[2] = f2bf(v0.z); w[3] = f2bf(v0.w);
                    w[4] = f2bf(v1.x); w[5] = f2bf(v1.y); w[6] = f2bf(v1.z); w[7] = f2bf(v1.w);
                    af[mt] = w;
                }
#pragma unroll
                for (int nh = 0; nh < 2; ++nh) {
                    s16x8 bg[4];
#pragma unroll
                    for (int nt = 0; nt < 4; ++nt) {
                        const int n = n0w + (nh * 4 + nt) * 16 + l16;
                        bg[nt] = *(const s16x8*)(Waxb + (size_t)n * 1024 + kb);
                    }
#pragma unroll
                    for (int mt = 0; mt < 4; ++mt)
#pragma unroll
                        for (int nt = 0; nt < 4; ++nt)
                            acc[mt][nh * 4 + nt] = MFMA16(af[mt], bg[nt], acc[mt][nh * 4 + nt]);
                }
            }
        }

        // ---- A-phase: acc += A[t-1] @ Waa^T  (A-frags from LDS state)
        if (j) {
#pragma unroll 2
            for (int kt = 0; kt < 16; ++kt) {
#pragma unroll
                for (int kc = 0; kc < 2; ++kc) {
                    const int slot = kt * 8 + kc * 4 + quad;   // 16B slot 0..127
                    const int kb = kt * 64 + kc * 32 + quad * 8;
                    s16x8 af[4];
#pragma unroll
                    for (int mt = 0; mt < 4; ++mt) {
                        const int r = 16 * mt + l16;
                        af[mt] = *(const s16x8*)((const char*)lA + r * 2048 + ((slot ^ (r & 7)) * 16));
                    }
#pragma unroll
                    for (int nh = 0; nh < 2; ++nh) {
                        s16x8 bg[4];
#pragma unroll
                        for (int nt = 0; nt < 4; ++nt) {
                            const int n = n0w + (nh * 4 + nt) * 16 + l16;
                            bg[nt] = *(const s16x8*)(Waab + (size_t)n * 1024 + kb);
                        }
#pragma unroll
                        for (int mt = 0; mt < 4; ++mt)
#pragma unroll
                            for (int nt = 0; nt < 4; ++nt)
                                acc[mt][nh * 4 + nt] = MFMA16(af[mt], bg[nt], acc[mt][nh * 4 + nt]);
                    }
                }
            }
        }

        __syncthreads();   // all waves done reading lA (previous state)

        // ---- write-back: A[t] -> lA (swizzled, feature dim n == next k) + UA
        bf16* gout = UA + (size_t)t * 65536;
#pragma unroll
        for (int mt = 0; mt < 4; ++mt)
#pragma unroll
            for (int rr = 0; rr < 4; ++rr) {
                const int m = 16 * mt + 4 * quad + rr;   // D row = 4*quad+rr
#pragma unroll
                for (int nt = 0; nt < 8; ++nt) {
                    const int n = n0w + nt * 16 + l16;   // D col = l16
                    const bf16 h = __float2bfloat16(acc[mt][nt][rr] + bv[nt]);
                    *(bf16*)((char*)lA + m * 2048 + (((n >> 3) ^ (m & 7)) * 16) + (n & 7) * 2) = h;
                    gout[(size_t)m * 1024 + n] = h;
                }
            }

        __syncthreads();   // lA update visible before next step's reads
    }
}

// ===========================================================================
// 8-phase counted-vmcnt 256^2 GEMM core (round-5 verified).  K-tile = 64.
// ===========================================================================
#define G8_READ_AF(mh) do { _Pragma("unroll") \
    for (int mt = 0; mt < 4; ++mt) { _Pragma("unroll") \
        for (int kc = 0; kc < 2; ++kc) { \
            const int r = 128 * wm + 16 * ((mh) * 4 + mt) + l16; \
            const int c = kc * 4 + quad; \
            af[mt][kc] = *(const s16x8*)((const char*)lA[curb] + r * 128 + ((c ^ (r & 7)) * 16)); \
        } } } while (0)

#define G8_READ_BG(nh) do { _Pragma("unroll") \
    for (int nt = 0; nt < 2; ++nt) { _Pragma("unroll") \
        for (int kc = 0; kc < 2; ++kc) { \
            const int r = 64 * wn + 16 * ((nh) * 2 + nt) + l16; \
            const int c = kc * 4 + quad; \
            bg[nt][kc] = *(const s16x8*)((const char*)lB[curb] + r * 128 + ((c ^ (r & 7)) * 16)); \
        } } } while (0)

#define G8_MFMA_Q(mh, nh) do { \
    __builtin_amdgcn_s_setprio(1); \
    _Pragma("unroll") \
    for (int mt = 0; mt < 4; ++mt) \
        _Pragma("unroll") \
        for (int nt = 0; nt < 2; ++nt) \
            _Pragma("unroll") \
            for (int kc = 0; kc < 2; ++kc) \
                acc[(mh) * 4 + mt][(nh) * 2 + nt] = \
                    MFMA16(af[mt][kc], bg[nt][kc], acc[(mh) * 4 + mt][(nh) * 2 + nt]); \
    __builtin_amdgcn_s_setprio(0); \
    } while (0)

#define G8_STAGE_A(Asrc, buf, h, ko) do { _Pragma("unroll") \
    for (int qi = 0; qi < 2; ++qi) { \
        const int q = (h) * 16 + wv * 2 + qi; \
        GLL16(Asrc + (size_t)(m0 + q * 8 + sr) * 1024 + (ko) + sc, (char*)lA[buf] + q * 1024); \
    } } while (0)
#define G8_STAGE_B(Bsrc, buf, h, ko) do { _Pragma("unroll") \
    for (int qi = 0; qi < 2; ++qi) { \
        const int q = (h) * 16 + wv * 2 + qi; \
        GLL16(Bsrc + (size_t)(n0 + q * 8 + sr) * 1024 + (ko) + sc, (char*)lB[buf] + q * 1024); \
    } } while (0)

#define G8_KLOOP(Asrc, Bsrc) \
    G8_STAGE_A(Asrc, 0, 0, 0);  G8_STAGE_A(Asrc, 0, 1, 0); \
    G8_STAGE_B(Bsrc, 0, 0, 0);  G8_STAGE_B(Bsrc, 0, 1, 0); \
    G8_STAGE_A(Asrc, 1, 0, 64); G8_STAGE_A(Asrc, 1, 1, 64); \
    asm volatile("s_waitcnt vmcnt(4)" ::: "memory"); \
    __builtin_amdgcn_s_barrier(); \
    for (int k = 0; k < 16; ++k) { \
        const int nxtb = curb ^ 1; \
        const int ko1 = (k + 1) * 64, ko2 = (k + 2) * 64; \
        G8_READ_AF(0); G8_READ_BG(0); \
        if (k < 15) G8_STAGE_B(Bsrc, nxtb, 0, ko1); \
        __builtin_amdgcn_s_barrier(); \
        G8_MFMA_Q(0, 0); \
        __builtin_amdgcn_s_barrier(); \
        G8_READ_BG(1); \
        if (k < 15) G8_STAGE_B(Bsrc, nxtb, 1, ko1); \
        __builtin_amdgcn_s_barrier(); \
        G8_MFMA_Q(0, 1); \
        __builtin_amdgcn_s_barrier(); \
        G8_READ_AF(1); \
        if (k < 14) G8_STAGE_A(Asrc, curb, 0, ko2); \
        __builtin_amdgcn_s_barrier(); \
        G8_MFMA_Q(1, 1); \
        __builtin_amdgcn_s_barrier(); \
        G8_READ_BG(0); \
        if (k < 14) G8_STAGE_A(Asrc, curb, 1, ko2); \
        __builtin_amdgcn_s_barrier(); \
        G8_MFMA_Q(1, 0); \
        if (k < 14)       { asm volatile("s_waitcnt vmcnt(4)" ::: "memory"); } \
        else if (k == 14) { asm volatile("s_waitcnt vmcnt(0)" ::: "memory"); } \
        __builtin_amdgcn_s_barrier(); \
        curb = nxtb; \
    }

// ---------------------------------------------------------------------------
// 8-phase GEMM:  C[om(m)][n] = bias[n] + sum_k A[m][k] * Bt[n][k]  (bf16 A)
// ---------------------------------------------------------------------------
template<bool OUT_F32, int REMAP>
__global__ __launch_bounds__(512, 2) void gemm8(
    const bf16* __restrict__ Ab, const bf16* __restrict__ Bt,
    const float* __restrict__ bias, void* __restrict__ Cp)
{
    __shared__ __align__(16) bf16 lA[2][256 * 64];
    __shared__ __align__(16) bf16 lB[2][256 * 64];

    const int tid  = threadIdx.x;
    const int lane = tid & 63, wv = tid >> 6;
    const int wm = wv >> 2, wn = wv & 3;
    const int quad = lane >> 4, l16 = lane & 15;

    const int lid = blockIdx.y * 128 + blockIdx.x;   // grid (128,4)
    const int wid = (lid & 7) * 64 + (lid >> 3);     // bijective, 512 % 8 == 0
    const int m0 = (wid >> 2) * 256;
    const int n0 = (wid & 3) * 256;

    const int sr = lane >> 3;
    const int sc = ((lane & 7) ^ sr) * 8;

    f32x4 acc[8][4] = {};
    s16x8 af[4][2], bg[2][2];
    int curb = 0;

    G8_KLOOP(Ab, Bt)

    float bv[4];
#pragma unroll
    for (int nt = 0; nt < 4; ++nt)
        bv[nt] = bias[n0 + 64 * wn + 16 * nt + l16];

#pragma unroll
    for (int mt = 0; mt < 8; ++mt) {
#pragma unroll
        for (int r = 0; r < 4; ++r) {
            const int m = m0 + 128 * wm + 16 * mt + 4 * quad + r;
            int om = m;
            if constexpr (REMAP == 1)      om = ((m & 511) << 6) | (m >> 9);
            else if constexpr (REMAP == 2) om = ((m & 63) << 9) | (m >> 6);
#pragma unroll
            for (int nt = 0; nt < 4; ++nt) {
                const int n = n0 + 64 * wn + 16 * nt + l16;
                const float val = acc[mt][nt][r] + bv[nt];
                if constexpr (OUT_F32) ((float*)Cp)[(size_t)om * 1024 + n] = val;
                else ((bf16*)Cp)[(size_t)om * 1024 + n] = __float2bfloat16(val);
            }
        }
    }
}

// ---------------------------------------------------------------------------
// 8-phase fix-up: UA[(c*16+j)*64+b][n] += sum_k CIN[c*64+b][k] * P_{j+1}[n][k]
// ---------------------------------------------------------------------------
__global__ __launch_bounds__(512, 2) void fixup8(
    const bf16* __restrict__ CIN, const bf16* __restrict__ PBase,
    bf16* __restrict__ UA)
{
    __shared__ __align__(16) bf16 lA[2][256 * 64];
    __shared__ __align__(16) bf16 lB[2][256 * 64];

    const int tid  = threadIdx.x;
    const int lane = tid & 63, wv = tid >> 6;
    const int wm = wv >> 2, wn = wv & 3;
    const int quad = lane >> 4, l16 = lane & 15;

    const int lid = blockIdx.y * 8 + blockIdx.x;    // 0..31 within z-slice
    const int wid = (lid & 7) * 4 + (lid >> 3);     // bijective, 32 % 8 == 0
    const int m0 = (wid >> 2) * 256;
    const int n0 = (wid & 3) * 256;

    const int j = blockIdx.z;
    const bf16* Bt = PBase + (size_t)j * 1048576;
    const int sr = lane >> 3;
    const int sc = ((lane & 7) ^ sr) * 8;

    f32x4 acc[8][4] = {};
    s16x8 af[4][2], bg[2][2];
    int curb = 0;

    G8_KLOOP(CIN, Bt)

#pragma unroll
    for (int mt = 0; mt < 8; ++mt)
#pragma unroll
        for (int r = 0; r < 4; ++r) {
            const int vm = m0 + 128 * wm + 16 * mt + 4 * quad + r;   // c*64 + b
            const size_t grow = (size_t)(((vm >> 6) * 16 + j) * 64 + (vm & 63));
#pragma unroll
            for (int nt = 0; nt < 4; ++nt) {
                const int n = n0 + 64 * wn + 16 * nt + l16;
                bf16* p = UA + grow * 1024 + n;
                *p = __float2bfloat16(acc[mt][nt][r] + __bfloat162float(*p));
            }
        }
}

// ---------------------------------------------------------------------------
// Power chain: D[z] = A[z] @ Bt^T.  dbuf-prefetch 128^2.  grid (8,8,z).
// ---------------------------------------------------------------------------
__global__ __launch_bounds__(256) void powmul(
    const bf16* __restrict__ Abase, const bf16* __restrict__ Bt,
    bf16* __restrict__ Dbase)
{
    __shared__ __align__(16) bf16 lA[2][128 * 64];
    __shared__ __align__(16) bf16 lB[2][128 * 64];
    const int tid  = threadIdx.x;
    const int lane = tid & 63, wv = tid >> 6;
    const int wm = wv & 1, wn = wv >> 1;
    const int quad = lane >> 4, l16 = lane & 15;
    const int m0 = blockIdx.x * 128, n0 = blockIdx.y * 128;
    const bf16* A = Abase + (size_t)blockIdx.z * 1048576;
    bf16* D       = Dbase + (size_t)blockIdx.z * 1048576;
    const int sr = lane >> 3;
    const int sc = ((lane & 7) ^ sr) * 8;

#define STAGE_AB(buf, ko) do { \
    _Pragma("unroll") \
    for (int qi = 0; qi < 4; ++qi) { \
        const int q = wv * 4 + qi; \
        GLL16(A  + (size_t)(m0 + q * 8 + sr) * 1024 + (ko) + sc, (char*)lA[buf] + q * 1024); \
        GLL16(Bt + (size_t)(n0 + q * 8 + sr) * 1024 + (ko) + sc, (char*)lB[buf] + q * 1024); \
    } } while (0)

    f32x4 acc[4][4] = {};
    STAGE_AB(0, 0);
    __syncthreads();
    int cur = 0;
    for (int t = 0; t < 16; ++t) {
        const int nxt = cur ^ 1;
        if (t < 15) STAGE_AB(nxt, (t + 1) * 64);
#pragma unroll
        for (int kc = 0; kc < 2; ++kc) {
            s16x8 af[4], bg[4];
#pragma unroll
            for (int mt = 0; mt < 4; ++mt) {
                const int r = 64 * wm + 16 * mt + l16;
                const int c = kc * 4 + quad;
                af[mt] = *(const s16x8*)((const char*)lA[cur] + r * 128 + ((c ^ (r & 7)) * 16));
            }
#pragma unroll
            for (int nt = 0; nt < 4; ++nt) {
                const int r = 64 * wn + 16 * nt + l16;
                const int c = kc * 4 + quad;
                bg[nt] = *(const s16x8*)((const char*)lB[cur] + r * 128 + ((c ^ (r & 7)) * 16));
            }
#pragma unroll
            for (int mt = 0; mt < 4; ++mt)
#pragma unroll
                for (int nt = 0; nt < 4; ++nt)
                    acc[mt][nt] = MFMA16(af[mt], bg[nt], acc[mt][nt]);
        }
        __syncthreads();
        cur = nxt;
    }
#undef STAGE_AB
#pragma unroll
    for (int mt = 0; mt < 4; ++mt)
#pragma unroll
        for (int r = 0; r < 4; ++r) {
            const int m = m0 + 64 * wm + 16 * mt + 4 * quad + r;
#pragma unroll
            for (int nt = 0; nt < 4; ++nt) {
                const int n = n0 + 64 * wn + 16 * nt + l16;
                D[(size_t)m * 1024 + n] = __float2bfloat16(acc[mt][nt][r]);
            }
        }
}

// ---------------------------------------------------------------------------
// Carry step: dst[b][n] = lend[b][n] + sum_k src[b][k] * P16[n][k]
// Launch-latency floor; unchanged.  256 blocks x 1 wave.
// ---------------------------------------------------------------------------
__global__ __launch_bounds__(64, 1) void carry_step(
    const bf16* __restrict__ P16, const bf16* __restrict__ lend,
    const bf16* __restrict__ src, bf16* __restrict__ dst)
{
    const int lane = threadIdx.x;
    const int quad = lane >> 4, l16 = lane & 15;
    const int bi = blockIdx.x & 3, nj = blockIdx.x >> 2;

    const bf16* arow = src + ((size_t)(16 * bi + l16)) * 1024;
    const bf16* wrow = P16 + ((size_t)(16 * nj + l16)) * 1024;

    const bf16* urow = lend + ((size_t)(16 * bi + 4 * quad)) * 1024 + 16 * nj + l16;
    f32x4 acc;
#pragma unroll
    for (int rr = 0; rr < 4; ++rr)
        acc[rr] = __bfloat162float(urow[(size_t)rr * 1024]);

    s16x8 av[32], wf[32];
#pragma unroll
    for (int kc = 0; kc < 32; ++kc) {
        av[kc] = *(const s16x8*)(arow + kc * 32 + quad * 8);
        wf[kc] = *(const s16x8*)(wrow + kc * 32 + quad * 8);
    }
#pragma unroll
    for (int kc = 0; kc < 32; ++kc)
        acc = MFMA16(av[kc], wf[kc], acc);

    bf16* drow = dst + ((size_t)(16 * bi + 4 * quad)) * 1024 + 16 * nj + l16;
#pragma unroll
    for (int rr = 0; rr < 4; ++rr)
        drow[(size_t)rr * 1024] = __float2bfloat16(acc[rr]);
}

// ---------------------------------------------------------------------------
// Blocked linear scan, S=16 chunk, G=32 chunks.
// Phase A + local scans fused into the persistent chunk_scan (1 launch).
// ---------------------------------------------------------------------------
extern "C" void kernel_launch(void* const* d_in, const int* in_sizes, int n_in,
                              void* d_out, int out_size, void* d_ws, size_t ws_size,
                              hipStream_t stream) {
    const float* X   = (const float*)d_in[0];   // [64,512,1024] f32
    const float* Wax = (const float*)d_in[1];   // [1024,1024]   f32
    const float* Waa = (const float*)d_in[2];   // [1024,1024]   f32
    const float* ba  = (const float*)d_in[3];   // [1024]        f32
    const float* Wy  = (const float*)d_in[4];   // [1024,1024]   f32
    const float* by  = (const float*)d_in[5];   // [1024]        f32

    char* ws = (char*)d_ws;
    bf16* UA   = (bf16*)ws;                       // 64 MB: [512][64][1024]
    bf16* PB   = (bf16*)(ws + 67108864);          // 32 MB: PB[k] = W^{k+1}, k=0..15
    bf16* Waxb = (bf16*)(ws + 100663296);         // 2 MB
    bf16* Wyb  = (bf16*)(ws + 102760448);         // 2 MB
    bf16* CIN  = (bf16*)(ws + 104857600);         // 4 MB: [32][64][1024] carry-in per chunk
    bf16* Tb   = CIN;                             // 2 MB transpose scratch (dead before carries)
    const size_t MM = 1048576;                    // elems per 1024x1024 matrix

    const int NW = 1024 * 1024;
    cvt_bf16<<<dim3(NW / 1024), dim3(256), 0, stream>>>(Wax, Waxb, NW);
    cvt_bf16<<<dim3(NW / 1024), dim3(256), 0, stream>>>(Waa, PB,   NW);   // PB[0] = W
    cvt_bf16<<<dim3(NW / 1024), dim3(256), 0, stream>>>(Wy,  Wyb,  NW);

    dim3 gridG(128, 4), blk2(512), blk(256);

    // Fused Phase A + local scans: A-chunk state resident in LDS, 1 launch.
    chunk_scan<<<dim3(32), blk2, 0, stream>>>(X, Waxb, PB, ba, UA);

    // Powers of W (log-depth; powers commute so only P_{2^k}^T is ever needed):
    transpose_bf16<<<dim3(16, 16), blk, 0, stream>>>(PB, Tb);              // W^T
    powmul<<<dim3(8, 8, 1), blk, 0, stream>>>(PB, Tb, PB + 1 * MM);        // P2 = W*W
    transpose_bf16<<<dim3(16, 16), blk, 0, stream>>>(PB + 1 * MM, Tb);     // P2^T
    powmul<<<dim3(8, 8, 2), blk, 0, stream>>>(PB, Tb, PB + 2 * MM);        // P3,P4 = {P1,P2}*P2
    transpose_bf16<<<dim3(16, 16), blk, 0, stream>>>(PB + 3 * MM, Tb);     // P4^T
    powmul<<<dim3(8, 8, 4), blk, 0, stream>>>(PB, Tb, PB + 4 * MM);        // P5..P8 = {P1..P4}*P4
    transpose_bf16<<<dim3(16, 16), blk, 0, stream>>>(PB + 7 * MM, Tb);     // P8^T
    powmul<<<dim3(8, 8, 8), blk, 0, stream>>>(PB, Tb, PB + 8 * MM);        // P9..P16 = {P1..P8}*P8

    // Carry scan over chunk ends: CIN[c] = A_end[c-1]; CIN[0] = 0.
    zero_bf16<<<dim3(32), dim3(256), 0, stream>>>(CIN, 65536);
    for (int c = 1; c < 32; ++c)
        carry_step<<<dim3(256), dim3(64), 0, stream>>>(
            PB + 15 * MM,
            UA  + (size_t)((c - 1) * 16 + 15) * 65536,
            CIN + (size_t)(c - 1) * 65536,
            CIN + (size_t)c * 65536);

    // Fix-up: UA[c*16+j] += CIN[c] @ (W^{j+1})^T, one parallel launch (8-phase).
    fixup8<<<dim3(8, 4, 16), blk2, 0, stream>>>(CIN, PB, UA);

    // Phase C: Y = A @ Wy^T + by    (rows t*64+b -> b*512+t, f32 out, 8-phase)
    gemm8<true, 2><<<gridG, blk2, 0, stream>>>(UA, Wyb, by, (float*)d_out);
}